// Round 1
// baseline (188.956 us; speedup 1.0000x reference)
//
#include <hip/hip_runtime.h>
#include <stdint.h>

typedef __attribute__((ext_vector_type(8))) short short8;        // 8 x bf16 (4 VGPRs)
typedef __attribute__((ext_vector_type(4))) float f32x4;
typedef __attribute__((ext_vector_type(4))) unsigned int u32x4;

#define MFMA16(a, b, c) __builtin_amdgcn_mfma_f32_16x16x32_bf16((a), (b), (c), 0, 0, 0)

static __device__ __forceinline__ unsigned short f2bf(float f) {
    union { float f; unsigned int u; } v; v.f = f;
    unsigned int u = v.u;
    unsigned int r = 0x7fffu + ((u >> 16) & 1u);
    return (unsigned short)((u + r) >> 16);
}

static __device__ __forceinline__ unsigned int cvt_pk_bf16(float lo, float hi) {
    unsigned int r;
    asm("v_cvt_pk_bf16_f32 %0, %1, %2" : "=v"(r) : "v"(lo), "v"(hi));
    return r;
}

static __device__ __forceinline__ short8 load_w_bf16(const float* row8) {
    const float4* p = (const float4*)row8;
    float4 lo = p[0], hi = p[1];
    short8 r;
    r[0] = (short)f2bf(lo.x); r[1] = (short)f2bf(lo.y);
    r[2] = (short)f2bf(lo.z); r[3] = (short)f2bf(lo.w);
    r[4] = (short)f2bf(hi.x); r[5] = (short)f2bf(hi.y);
    r[6] = (short)f2bf(hi.z); r[7] = (short)f2bf(hi.w);
    return r;
}

// ---------------- Kernel 1: x[B,256,4096] f32 -> xT[B,4096,256] bf16 ----------------
__global__ __launch_bounds__(256) void k_transpose(const float* __restrict__ x,
                                                   unsigned short* __restrict__ xT) {
    __shared__ float lds[32][33];
    const int b = blockIdx.z, ct = blockIdx.y, nt = blockIdx.x;
    const int tx = threadIdx.x & 31, ty = threadIdx.x >> 5;   // ty 0..7
    const float* xb = x + ((size_t)b * 256 + ct * 32) * 4096 + nt * 32;
#pragma unroll
    for (int k = 0; k < 4; ++k)
        lds[ty + 8 * k][tx] = xb[(size_t)(ty + 8 * k) * 4096 + tx];
    __syncthreads();
    unsigned short* o = xT + ((size_t)b * 4096 + nt * 32) * 256 + ct * 32;
#pragma unroll
    for (int k = 0; k < 4; ++k)
        o[(size_t)(ty + 8 * k) * 256 + tx] = f2bf(lds[tx][ty + 8 * k]);
}

// ---------------- Kernel 2: q/k projections -> qT,kT [B,4096,32] bf16 ----------------
// D-tile = [16 n x 16 o]; A = xT chunk (rows n), B = W^T (cols o).
__global__ __launch_bounds__(256) void k_proj_qk(const unsigned short* __restrict__ xT,
                                                 const float* __restrict__ Wq, const float* __restrict__ bq,
                                                 const float* __restrict__ Wk, const float* __restrict__ bk,
                                                 unsigned short* __restrict__ qT,
                                                 unsigned short* __restrict__ kT) {
    const int b = blockIdx.y;
    const int ntile = blockIdx.x;                 // 64 n per block
    const int lane = threadIdx.x & 63;
    const int wv = threadIdx.x >> 6;
    const int l15 = lane & 15, g = lane >> 4;
    const int n0 = ntile * 64 + wv * 16;
    const unsigned short* xrow = xT + ((size_t)b * 4096 + n0 + l15) * 256;

    f32x4 acc[4] = {};
    for (int k0 = 0; k0 < 256; k0 += 32) {
        const short8 a = *(const short8*)(xrow + k0 + g * 8);
#pragma unroll
        for (int ot = 0; ot < 4; ++ot) {
            const float* wr = (ot < 2) ? (Wq + (size_t)(ot * 16 + l15) * 256)
                                       : (Wk + (size_t)((ot - 2) * 16 + l15) * 256);
            const short8 bb = load_w_bf16(wr + k0 + g * 8);
            acc[ot] = MFMA16(a, bb, acc[ot]);
        }
    }
#pragma unroll
    for (int ot = 0; ot < 4; ++ot) {
        const int o = (ot & 1) * 16 + l15;        // 0..31 within q or k
        const float bias = (ot < 2) ? bq[o] : bk[o];
        unsigned short* dst = (ot < 2) ? qT : kT;
#pragma unroll
        for (int r = 0; r < 4; ++r) {
            const int n = n0 + g * 4 + r;
            dst[((size_t)b * 4096 + n) * 32 + o] = f2bf(acc[ot][r] + bias);
        }
    }
}

// ---------------- Kernel 3: v projection -> vp [B,256,4096] bf16 ----------------
__global__ __launch_bounds__(256) void k_proj_v(const unsigned short* __restrict__ xT,
                                                const float* __restrict__ Wv, const float* __restrict__ bv,
                                                unsigned short* __restrict__ vp) {
    const int b = blockIdx.z;
    const int ctile = blockIdx.y;                 // 4: c0 base
    const int ntile = blockIdx.x;                 // 64
    const int lane = threadIdx.x & 63;
    const int wv = threadIdx.x >> 6;
    const int l15 = lane & 15, g = lane >> 4;
    const int c0 = ctile * 64 + wv * 16;
    const int n0 = ntile * 64;
    const float* wrow = Wv + (size_t)(c0 + l15) * 256;
    const unsigned short* xbase = xT + ((size_t)b * 4096 + n0) * 256;

    f32x4 acc[4] = {};
    for (int k0 = 0; k0 < 256; k0 += 32) {
        const short8 a = load_w_bf16(wrow + k0 + g * 8);
#pragma unroll
        for (int nt = 0; nt < 4; ++nt) {
            const short8 bb = *(const short8*)(xbase + (size_t)(nt * 16 + l15) * 256 + k0 + g * 8);
            acc[nt] = MFMA16(a, bb, acc[nt]);
        }
    }
#pragma unroll
    for (int nt = 0; nt < 4; ++nt)
#pragma unroll
        for (int r = 0; r < 4; ++r) {
            const int c = c0 + g * 4 + r;
            const int n = n0 + nt * 16 + l15;
            vp[((size_t)b * 256 + c) * 4096 + n] = f2bf(acc[nt][r] + bv[c]);
        }
}

// ---------------- Kernel 4: flash attention (swapped operands) ----------------
// S^T[i,m] = sum_d qT[i,d] * kT[m,d];  softmax over i;  O^T[c,m] = sum_i v[c,i] P^T[i,m]
__global__ __launch_bounds__(256) void k_attn(const unsigned short* __restrict__ qT,
                                              const unsigned short* __restrict__ kT,
                                              const unsigned short* __restrict__ vp,
                                              const float* __restrict__ x,
                                              const float* __restrict__ gamma,
                                              float* __restrict__ out) {
    __shared__ unsigned short vlds[256 * 64];     // [c][64 i] bf16, 16B-chunk XOR swizzle, 32 KiB

    const int b = blockIdx.y;
    const int mt = blockIdx.x;
    const int tid = threadIdx.x;
    const int lane = tid & 63;
    const int wv = tid >> 6;
    const int l15 = lane & 15, g = lane >> 4;
    const int m_base = mt * 64 + wv * 16;

    const unsigned short* qTb = qT + (size_t)b * 4096 * 32;
    const unsigned short* vpb = vp + (size_t)b * 256 * 4096;

    // hoisted QK^T B-frag: B[d][m'] = kT[m_base + l15][d], d = g*8..g*8+7
    const short8 qkB = *(const short8*)(kT + ((size_t)b * 4096 + m_base + l15) * 32 + g * 8);

    f32x4 oacc[16] = {};
    float m_run = -1e30f;
    float l_run = 0.0f;

    const int srcA = l15 + 16 * ((g & 1) * 2);    // shuffle sources (w<2)
    const int srcB = srcA + 16;                   // (w>=2)
    const bool hiHalf = (g >= 2);

    for (int i0 = 0; i0 < 4096; i0 += 64) {
        // ---- stage V tile [256 c][64 i] into LDS, swizzled ----
        __syncthreads();
#pragma unroll
        for (int s = 0; s < 8; ++s) {
            const int q = tid + 256 * s;          // 16B chunk id, 0..2047
            const int c = q >> 3;
            const int jc = q & 7;                 // slot
            const int jd = jc ^ (c & 7);          // logical i-chunk stored in this slot
            const u32x4 d = *(const u32x4*)(vpb + (size_t)c * 4096 + i0 + jd * 8);
            *(u32x4*)(vlds + c * 64 + jc * 8) = d;
        }
        __syncthreads();

        // ---- QK^T: 4 tiles of S^T [16 i x 16 m] ----
        f32x4 s4[4];
#pragma unroll
        for (int it = 0; it < 4; ++it) {
            const short8 a = *(const short8*)(qTb + (size_t)(i0 + it * 16 + l15) * 32 + g * 8);
            f32x4 z = {0.f, 0.f, 0.f, 0.f};
            s4[it] = MFMA16(a, qkB, z);
        }

        // ---- online softmax over i; every reg this lane holds has m = m_base + l15 ----
        float mx = -1e30f;
#pragma unroll
        for (int it = 0; it < 4; ++it)
#pragma unroll
            for (int r = 0; r < 4; ++r) mx = fmaxf(mx, s4[it][r]);
        mx = fmaxf(mx, __shfl_xor(mx, 16));
        mx = fmaxf(mx, __shfl_xor(mx, 32));
        const float m_new = fmaxf(m_run, mx);
        const float corr = __expf(m_run - m_new);

        float p[4][4];
        float sum = 0.f;
#pragma unroll
        for (int it = 0; it < 4; ++it)
#pragma unroll
            for (int r = 0; r < 4; ++r) {
                p[it][r] = __expf(s4[it][r] - m_new);
                sum += p[it][r];
            }
        sum += __shfl_xor(sum, 16);
        sum += __shfl_xor(sum, 32);
        l_run = l_run * corr + sum;

        if (!__all(m_new == m_run)) {
#pragma unroll
            for (int t = 0; t < 16; ++t) {
                oacc[t][0] *= corr; oacc[t][1] *= corr;
                oacc[t][2] *= corr; oacc[t][3] *= corr;
            }
        }
        m_run = m_new;

        // ---- pack P^T to bf16 pairs: pk[it][q] = (p[it][2q] | p[it][2q+1]<<16) ----
        unsigned int pk[4][2];
#pragma unroll
        for (int it = 0; it < 4; ++it) {
            pk[it][0] = cvt_pk_bf16(p[it][0], p[it][1]);
            pk[it][1] = cvt_pk_bf16(p[it][2], p[it][3]);
        }

        // ---- build PV B-frags [32 i x 16 m] via cross-lane redistribution ----
        short8 pb[2];
#pragma unroll
        for (int f = 0; f < 2; ++f) {
            unsigned int wds[4];
#pragma unroll
            for (int wd = 0; wd < 4; ++wd) {
                const int src = (wd < 2) ? srcA : srcB;
                const unsigned int t0 = __shfl(pk[2 * f + 0][wd & 1], src);
                const unsigned int t1 = __shfl(pk[2 * f + 1][wd & 1], src);
                wds[wd] = hiHalf ? t1 : t0;
            }
            const u32x4 u = {wds[0], wds[1], wds[2], wds[3]};
            pb[f] = __builtin_bit_cast(short8, u);
        }

        // ---- PV: O^T[c][m] += V[c][i] * P^T[i][m] ----
#pragma unroll
        for (int ct = 0; ct < 16; ++ct) {
            const int c = ct * 16 + l15;
#pragma unroll
            for (int f = 0; f < 2; ++f) {
                const int slot = (f * 4 + g) ^ (c & 7);
                const short8 va = *(const short8*)(vlds + c * 64 + slot * 8);
                oacc[ct] = MFMA16(va, pb[f], oacc[ct]);
            }
        }
    }

    // ---- epilogue: out = gamma * O/l + x ----
    const float g0 = gamma[0];
    const float inv_l = 1.0f / l_run;
    const int m = m_base + l15;
    const float* xb = x + (size_t)b * 256 * 4096;
    float* ob = out + (size_t)b * 256 * 4096;
#pragma unroll
    for (int ct = 0; ct < 16; ++ct)
#pragma unroll
        for (int r = 0; r < 4; ++r) {
            const int c = ct * 16 + g * 4 + r;
            const size_t idx = (size_t)c * 4096 + m;
            ob[idx] = g0 * oacc[ct][r] * inv_l + xb[idx];
        }
}

extern "C" void kernel_launch(void* const* d_in, const int* in_sizes, int n_in,
                              void* d_out, int out_size, void* d_ws, size_t ws_size,
                              hipStream_t stream) {
    (void)in_sizes; (void)n_in; (void)out_size; (void)ws_size;
    const float* x     = (const float*)d_in[0];
    const float* Wq    = (const float*)d_in[1];
    const float* bq    = (const float*)d_in[2];
    const float* Wk    = (const float*)d_in[3];
    const float* bk    = (const float*)d_in[4];
    const float* Wv    = (const float*)d_in[5];
    const float* bv    = (const float*)d_in[6];
    const float* gamma = (const float*)d_in[7];
    float* out = (float*)d_out;

    unsigned short* xT = (unsigned short*)d_ws;                       // 4*4096*256 bf16
    unsigned short* qT = xT + (size_t)4 * 4096 * 256;                 // 4*4096*32
    unsigned short* kT = qT + (size_t)4 * 4096 * 32;                  // 4*4096*32
    unsigned short* vp = kT + (size_t)4 * 4096 * 32;                  // 4*256*4096

    k_transpose<<<dim3(128, 8, 4), 256, 0, stream>>>(x, xT);
    k_proj_qk<<<dim3(64, 4), 256, 0, stream>>>(xT, Wq, bq, Wk, bk, qT, kT);
    k_proj_v<<<dim3(64, 4, 4), 256, 0, stream>>>(xT, Wv, bv, vp);
    k_attn<<<dim3(64, 4), 256, 0, stream>>>(qT, kT, vp, x, gamma, out);
}

// Round 2
// 155.032 us; speedup vs baseline: 1.2188x; 1.2188x over previous
//
#include <hip/hip_runtime.h>
#include <stdint.h>

typedef __attribute__((ext_vector_type(8))) short short8;        // 8 x bf16 (4 VGPRs)
typedef __attribute__((ext_vector_type(4))) float f32x4;
typedef __attribute__((ext_vector_type(4))) unsigned int u32x4;

#define MFMA16(a, b, c) __builtin_amdgcn_mfma_f32_16x16x32_bf16((a), (b), (c), 0, 0, 0)

static __device__ __forceinline__ unsigned short f2bf(float f) {
    union { float f; unsigned int u; } v; v.f = f;
    unsigned int u = v.u;
    unsigned int r = 0x7fffu + ((u >> 16) & 1u);
    return (unsigned short)((u + r) >> 16);
}

static __device__ __forceinline__ float bf2f(unsigned short s) {
    union { unsigned int u; float f; } v; v.u = ((unsigned int)s) << 16;
    return v.f;
}

static __device__ __forceinline__ unsigned int cvt_pk_bf16(float lo, float hi) {
    unsigned int r;
    asm("v_cvt_pk_bf16_f32 %0, %1, %2" : "=v"(r) : "v"(lo), "v"(hi));
    return r;
}

static __device__ __forceinline__ short8 load_w_bf16(const float* row8) {
    const float4* p = (const float4*)row8;
    float4 lo = p[0], hi = p[1];
    short8 r;
    r[0] = (short)f2bf(lo.x); r[1] = (short)f2bf(lo.y);
    r[2] = (short)f2bf(lo.z); r[3] = (short)f2bf(lo.w);
    r[4] = (short)f2bf(hi.x); r[5] = (short)f2bf(hi.y);
    r[6] = (short)f2bf(hi.z); r[7] = (short)f2bf(hi.w);
    return r;
}

// ---------------- Kernel 1: x[B,256,4096] f32 -> xT[B,4096,256] bf16 ----------------
__global__ __launch_bounds__(256) void k_transpose(const float* __restrict__ x,
                                                   unsigned short* __restrict__ xT) {
    __shared__ float lds[32][33];
    const int b = blockIdx.z, ct = blockIdx.y, nt = blockIdx.x;
    const int tx = threadIdx.x & 31, ty = threadIdx.x >> 5;   // ty 0..7
    const float* xb = x + ((size_t)b * 256 + ct * 32) * 4096 + nt * 32;
#pragma unroll
    for (int k = 0; k < 4; ++k)
        lds[ty + 8 * k][tx] = xb[(size_t)(ty + 8 * k) * 4096 + tx];
    __syncthreads();
    unsigned short* o = xT + ((size_t)b * 4096 + nt * 32) * 256 + ct * 32;
#pragma unroll
    for (int k = 0; k < 4; ++k)
        o[(size_t)(ty + 8 * k) * 256 + tx] = f2bf(lds[tx][ty + 8 * k]);
}

// ---------------- Kernel 2: q/k projections -> qT,kT [B,4096,32] bf16 ----------------
__global__ __launch_bounds__(256) void k_proj_qk(const unsigned short* __restrict__ xT,
                                                 const float* __restrict__ Wq, const float* __restrict__ bq,
                                                 const float* __restrict__ Wk, const float* __restrict__ bk,
                                                 unsigned short* __restrict__ qT,
                                                 unsigned short* __restrict__ kT) {
    const int b = blockIdx.y;
    const int ntile = blockIdx.x;                 // 64 n per block
    const int lane = threadIdx.x & 63;
    const int wv = threadIdx.x >> 6;
    const int l15 = lane & 15, g = lane >> 4;
    const int n0 = ntile * 64 + wv * 16;
    const unsigned short* xrow = xT + ((size_t)b * 4096 + n0 + l15) * 256;

    f32x4 acc[4] = {};
    for (int k0 = 0; k0 < 256; k0 += 32) {
        const short8 a = *(const short8*)(xrow + k0 + g * 8);
#pragma unroll
        for (int ot = 0; ot < 4; ++ot) {
            const float* wr = (ot < 2) ? (Wq + (size_t)(ot * 16 + l15) * 256)
                                       : (Wk + (size_t)((ot - 2) * 16 + l15) * 256);
            const short8 bb = load_w_bf16(wr + k0 + g * 8);
            acc[ot] = MFMA16(a, bb, acc[ot]);
        }
    }
#pragma unroll
    for (int ot = 0; ot < 4; ++ot) {
        const int o = (ot & 1) * 16 + l15;        // 0..31 within q or k
        const float bias = (ot < 2) ? bq[o] : bk[o];
        unsigned short* dst = (ot < 2) ? qT : kT;
#pragma unroll
        for (int r = 0; r < 4; ++r) {
            const int n = n0 + g * 4 + r;
            dst[((size_t)b * 4096 + n) * 32 + o] = f2bf(acc[ot][r] + bias);
        }
    }
}

// ---------------- Kernel 3: v projection -> vp [B,256,4096] bf16 ----------------
__global__ __launch_bounds__(256) void k_proj_v(const unsigned short* __restrict__ xT,
                                                const float* __restrict__ Wv, const float* __restrict__ bv,
                                                unsigned short* __restrict__ vp) {
    const int b = blockIdx.z;
    const int ctile = blockIdx.y;                 // 4: c0 base
    const int ntile = blockIdx.x;                 // 64
    const int lane = threadIdx.x & 63;
    const int wv = threadIdx.x >> 6;
    const int l15 = lane & 15, g = lane >> 4;
    const int c0 = ctile * 64 + wv * 16;
    const int n0 = ntile * 64;
    const float* wrow = Wv + (size_t)(c0 + l15) * 256;
    const unsigned short* xbase = xT + ((size_t)b * 4096 + n0) * 256;

    f32x4 acc[4] = {};
    for (int k0 = 0; k0 < 256; k0 += 32) {
        const short8 a = load_w_bf16(wrow + k0 + g * 8);
#pragma unroll
        for (int nt = 0; nt < 4; ++nt) {
            const short8 bb = *(const short8*)(xbase + (size_t)(nt * 16 + l15) * 256 + k0 + g * 8);
            acc[nt] = MFMA16(a, bb, acc[nt]);
        }
    }
#pragma unroll
    for (int nt = 0; nt < 4; ++nt)
#pragma unroll
        for (int r = 0; r < 4; ++r) {
            const int c = c0 + g * 4 + r;
            const int n = n0 + nt * 16 + l15;
            vp[((size_t)b * 256 + c) * 4096 + n] = f2bf(acc[nt][r] + bv[c]);
        }
}

// ---------------- Kernel 4: flash attention, split over i (flash-decoding) ----------------
// S^T[i,m] = sum_d qT[i,d]*kT[m,d]; online softmax over i within this split's chunk;
// partial O^T[c,m] (raw, bf16) + (m_run, l_run) per m written to workspace.
__global__ __launch_bounds__(256) void k_attn(const unsigned short* __restrict__ qT,
                                              const unsigned short* __restrict__ kT,
                                              const unsigned short* __restrict__ vp,
                                              unsigned short* __restrict__ Opart,
                                              float* __restrict__ ml,
                                              int ilen) {
    __shared__ unsigned short vlds[256 * 64];     // [c][64 i] bf16, 16B-chunk XOR swizzle, 32 KiB

    const int b = blockIdx.y;
    const int mt = blockIdx.x;
    const int sp = blockIdx.z;                    // split index
    const int tid = threadIdx.x;
    const int lane = tid & 63;
    const int wv = tid >> 6;
    const int l15 = lane & 15, g = lane >> 4;
    const int m_base = mt * 64 + wv * 16;
    const int i_start = sp * ilen;

    const unsigned short* qTb = qT + (size_t)b * 4096 * 32;
    const unsigned short* vpb = vp + (size_t)b * 256 * 4096;

    // hoisted QK^T B-frag: B[d][m'] = kT[m_base + l15][d], d = g*8..g*8+7
    const short8 qkB = *(const short8*)(kT + ((size_t)b * 4096 + m_base + l15) * 32 + g * 8);

    f32x4 oacc[16] = {};
    float m_run = -1e30f;
    float l_run = 0.0f;

    const int srcA = l15 + 16 * ((g & 1) * 2);    // shuffle sources (w<2)
    const int srcB = srcA + 16;                   // (w>=2)
    const bool hiHalf = (g >= 2);

    for (int i0 = i_start; i0 < i_start + ilen; i0 += 64) {
        // ---- stage V tile [256 c][64 i] into LDS, swizzled ----
        __syncthreads();
#pragma unroll
        for (int s = 0; s < 8; ++s) {
            const int q = tid + 256 * s;          // 16B chunk id, 0..2047
            const int c = q >> 3;
            const int jc = q & 7;                 // slot
            const int jd = jc ^ (c & 7);          // logical i-chunk stored in this slot
            const u32x4 d = *(const u32x4*)(vpb + (size_t)c * 4096 + i0 + jd * 8);
            *(u32x4*)(vlds + c * 64 + jc * 8) = d;
        }
        __syncthreads();

        // ---- QK^T: 4 tiles of S^T [16 i x 16 m] ----
        f32x4 s4[4];
#pragma unroll
        for (int it = 0; it < 4; ++it) {
            const short8 a = *(const short8*)(qTb + (size_t)(i0 + it * 16 + l15) * 32 + g * 8);
            f32x4 z = {0.f, 0.f, 0.f, 0.f};
            s4[it] = MFMA16(a, qkB, z);
        }

        // ---- online softmax over i; every reg this lane holds has m = m_base + l15 ----
        float mx = -1e30f;
#pragma unroll
        for (int it = 0; it < 4; ++it)
#pragma unroll
            for (int r = 0; r < 4; ++r) mx = fmaxf(mx, s4[it][r]);
        mx = fmaxf(mx, __shfl_xor(mx, 16));
        mx = fmaxf(mx, __shfl_xor(mx, 32));
        const float m_new = fmaxf(m_run, mx);
        const float corr = __expf(m_run - m_new);

        float p[4][4];
        float sum = 0.f;
#pragma unroll
        for (int it = 0; it < 4; ++it)
#pragma unroll
            for (int r = 0; r < 4; ++r) {
                p[it][r] = __expf(s4[it][r] - m_new);
                sum += p[it][r];
            }
        sum += __shfl_xor(sum, 16);
        sum += __shfl_xor(sum, 32);
        l_run = l_run * corr + sum;

        if (!__all(m_new == m_run)) {
#pragma unroll
            for (int t = 0; t < 16; ++t) {
                oacc[t][0] *= corr; oacc[t][1] *= corr;
                oacc[t][2] *= corr; oacc[t][3] *= corr;
            }
        }
        m_run = m_new;

        // ---- pack P^T to bf16 pairs ----
        unsigned int pk[4][2];
#pragma unroll
        for (int it = 0; it < 4; ++it) {
            pk[it][0] = cvt_pk_bf16(p[it][0], p[it][1]);
            pk[it][1] = cvt_pk_bf16(p[it][2], p[it][3]);
        }

        // ---- build PV B-frags [32 i x 16 m] via cross-lane redistribution ----
        short8 pb[2];
#pragma unroll
        for (int f = 0; f < 2; ++f) {
            unsigned int wds[4];
#pragma unroll
            for (int wd = 0; wd < 4; ++wd) {
                const int src = (wd < 2) ? srcA : srcB;
                const unsigned int t0 = __shfl(pk[2 * f + 0][wd & 1], src);
                const unsigned int t1 = __shfl(pk[2 * f + 1][wd & 1], src);
                wds[wd] = hiHalf ? t1 : t0;
            }
            const u32x4 u = {wds[0], wds[1], wds[2], wds[3]};
            pb[f] = __builtin_bit_cast(short8, u);
        }

        // ---- PV: O^T[c][m] += V[c][i] * P^T[i][m] ----
#pragma unroll
        for (int ct = 0; ct < 16; ++ct) {
            const int c = ct * 16 + l15;
#pragma unroll
            for (int f = 0; f < 2; ++f) {
                const int slot = (f * 4 + g) ^ (c & 7);
                const short8 va = *(const short8*)(vlds + c * 64 + slot * 8);
                oacc[ct] = MFMA16(va, pb[f], oacc[ct]);
            }
        }
    }

    // ---- epilogue: write raw partial O (bf16) and (m_run, l_run) ----
    const int m = m_base + l15;
    unsigned short* Ob = Opart + ((size_t)(sp * 4 + b) * 256) * 4096;
#pragma unroll
    for (int ct = 0; ct < 16; ++ct)
#pragma unroll
        for (int r = 0; r < 4; ++r) {
            const int c = ct * 16 + g * 4 + r;
            Ob[(size_t)c * 4096 + m] = f2bf(oacc[ct][r]);
        }
    if (lane < 16) {
        const size_t mi = ((size_t)(sp * 4 + b) * 4096 + m) * 2;
        ml[mi]     = m_run;
        ml[mi + 1] = l_run;
    }
}

// ---------------- Kernel 5: combine partials + normalize + gamma*O + x ----------------
__global__ __launch_bounds__(256) void k_combine(const unsigned short* __restrict__ Opart,
                                                 const float* __restrict__ ml,
                                                 const float* __restrict__ x,
                                                 const float* __restrict__ gamma,
                                                 float* __restrict__ out, int S) {
    const size_t idx = (size_t)blockIdx.x * 256 + threadIdx.x;   // (b*256 + c)*4096 + m
    const int m = (int)(idx & 4095);
    const int b = (int)(idx >> 20);

    float M = -1e30f;
    for (int s = 0; s < S; ++s)
        M = fmaxf(M, ml[((size_t)(s * 4 + b) * 4096 + m) * 2]);

    float L = 0.f, O = 0.f;
    for (int s = 0; s < S; ++s) {
        const size_t mi = ((size_t)(s * 4 + b) * 4096 + m) * 2;
        const float w = __expf(ml[mi] - M);
        L += w * ml[mi + 1];
        O += w * bf2f(Opart[(size_t)s * 4194304 + idx]);
    }
    out[idx] = gamma[0] * O / L + x[idx];
}

extern "C" void kernel_launch(void* const* d_in, const int* in_sizes, int n_in,
                              void* d_out, int out_size, void* d_ws, size_t ws_size,
                              hipStream_t stream) {
    (void)in_sizes; (void)n_in; (void)out_size;
    const float* x     = (const float*)d_in[0];
    const float* Wq    = (const float*)d_in[1];
    const float* bq    = (const float*)d_in[2];
    const float* Wk    = (const float*)d_in[3];
    const float* bk    = (const float*)d_in[4];
    const float* Wv    = (const float*)d_in[5];
    const float* bv    = (const float*)d_in[6];
    const float* gamma = (const float*)d_in[7];
    float* out = (float*)d_out;

    unsigned short* xT = (unsigned short*)d_ws;                       // 4*4096*256 bf16
    unsigned short* qT = xT + (size_t)4 * 4096 * 256;                 // 4*4096*32
    unsigned short* kT = qT + (size_t)4 * 4096 * 32;                  // 4*4096*32
    unsigned short* vp = kT + (size_t)4 * 4096 * 32;                  // 4*256*4096
    unsigned short* Opart = vp + (size_t)4 * 256 * 4096;              // S * 4*256*4096 bf16

    const size_t base_bytes = ((size_t)4 * 4096 * 256 * 2 + (size_t)4 * 256 * 4096) * 2;
    auto need = [&](int s) {
        return base_bytes + (size_t)s * 4194304 * 2 + (size_t)s * 4 * 4096 * 2 * sizeof(float);
    };
    int S = (need(4) <= ws_size) ? 4 : (need(2) <= ws_size ? 2 : 1);
    float* ml = (float*)(Opart + (size_t)S * 4194304);

    k_transpose<<<dim3(128, 8, 4), 256, 0, stream>>>(x, xT);
    k_proj_qk<<<dim3(64, 4), 256, 0, stream>>>(xT, Wq, bq, Wk, bk, qT, kT);
    k_proj_v<<<dim3(64, 4, 4), 256, 0, stream>>>(xT, Wv, bv, vp);
    k_attn<<<dim3(64, 4, S), 256, 0, stream>>>(qT, kT, vp, Opart, ml, 4096 / S);
    k_combine<<<dim3(16384), 256, 0, stream>>>(Opart, ml, x, gamma, out, S);
}

// Round 4
// 151.543 us; speedup vs baseline: 1.2469x; 1.0230x over previous
//
#include <hip/hip_runtime.h>
#include <stdint.h>

typedef __attribute__((ext_vector_type(8))) short short8;        // 8 x bf16 (4 VGPRs)
typedef __attribute__((ext_vector_type(4))) float f32x4;
typedef __attribute__((ext_vector_type(4))) unsigned int u32x4;

#define MFMA16(a, b, c) __builtin_amdgcn_mfma_f32_16x16x32_bf16((a), (b), (c), 0, 0, 0)

#define GLOAD_LDS16(gsrc, ldst)                                                        \
    __builtin_amdgcn_global_load_lds(                                                  \
        (const __attribute__((address_space(1))) unsigned int*)(gsrc),                 \
        (__attribute__((address_space(3))) unsigned int*)(ldst), 16, 0, 0)

#define LOG2E 1.4426950408889634f

static __device__ __forceinline__ unsigned short f2bf(float f) {
    union { float f; unsigned int u; } v; v.f = f;
    unsigned int u = v.u;
    unsigned int r = 0x7fffu + ((u >> 16) & 1u);
    return (unsigned short)((u + r) >> 16);
}

static __device__ __forceinline__ float bf2f(unsigned short s) {
    union { unsigned int u; float f; } v; v.u = ((unsigned int)s) << 16;
    return v.f;
}

static __device__ __forceinline__ unsigned int cvt_pk_bf16(float lo, float hi) {
    unsigned int r;
    asm("v_cvt_pk_bf16_f32 %0, %1, %2" : "=v"(r) : "v"(lo), "v"(hi));
    return r;
}

static __device__ __forceinline__ short8 load_w_bf16(const float* row8) {
    const float4* p = (const float4*)row8;
    float4 lo = p[0], hi = p[1];
    short8 r;
    r[0] = (short)f2bf(lo.x); r[1] = (short)f2bf(lo.y);
    r[2] = (short)f2bf(lo.z); r[3] = (short)f2bf(lo.w);
    r[4] = (short)f2bf(hi.x); r[5] = (short)f2bf(hi.y);
    r[6] = (short)f2bf(hi.z); r[7] = (short)f2bf(hi.w);
    return r;
}

// ---------------- Kernel 1: x[B,256,4096] f32 -> xT[B,4096,256] bf16 ----------------
__global__ __launch_bounds__(256) void k_transpose(const float* __restrict__ x,
                                                   unsigned short* __restrict__ xT) {
    __shared__ float lds[32][33];
    const int b = blockIdx.z, ct = blockIdx.y, nt = blockIdx.x;
    const int tx = threadIdx.x & 31, ty = threadIdx.x >> 5;   // ty 0..7
    const float* xb = x + ((size_t)b * 256 + ct * 32) * 4096 + nt * 32;
#pragma unroll
    for (int k = 0; k < 4; ++k)
        lds[ty + 8 * k][tx] = xb[(size_t)(ty + 8 * k) * 4096 + tx];
    __syncthreads();
    unsigned short* o = xT + ((size_t)b * 4096 + nt * 32) * 256 + ct * 32;
#pragma unroll
    for (int k = 0; k < 4; ++k)
        o[(size_t)(ty + 8 * k) * 256 + tx] = f2bf(lds[tx][ty + 8 * k]);
}

// ---------------- Kernel 2: q/k projections -> qT,kT [B,4096,32] bf16 ----------------
// q is pre-scaled by log2(e) so attention can use exp2.
__global__ __launch_bounds__(256) void k_proj_qk(const unsigned short* __restrict__ xT,
                                                 const float* __restrict__ Wq, const float* __restrict__ bq,
                                                 const float* __restrict__ Wk, const float* __restrict__ bk,
                                                 unsigned short* __restrict__ qT,
                                                 unsigned short* __restrict__ kT) {
    const int b = blockIdx.y;
    const int ntile = blockIdx.x;                 // 64 n per block
    const int lane = threadIdx.x & 63;
    const int wv = threadIdx.x >> 6;
    const int l15 = lane & 15, g = lane >> 4;
    const int n0 = ntile * 64 + wv * 16;
    const unsigned short* xrow = xT + ((size_t)b * 4096 + n0 + l15) * 256;

    f32x4 acc[4] = {};
    for (int k0 = 0; k0 < 256; k0 += 32) {
        const short8 a = *(const short8*)(xrow + k0 + g * 8);
#pragma unroll
        for (int ot = 0; ot < 4; ++ot) {
            const float* wr = (ot < 2) ? (Wq + (size_t)(ot * 16 + l15) * 256)
                                       : (Wk + (size_t)((ot - 2) * 16 + l15) * 256);
            const short8 bb = load_w_bf16(wr + k0 + g * 8);
            acc[ot] = MFMA16(a, bb, acc[ot]);
        }
    }
#pragma unroll
    for (int ot = 0; ot < 4; ++ot) {
        const int o = (ot & 1) * 16 + l15;        // 0..31 within q or k
        const float bias = (ot < 2) ? bq[o] : bk[o];
        const float sc = (ot < 2) ? LOG2E : 1.0f;
        unsigned short* dst = (ot < 2) ? qT : kT;
#pragma unroll
        for (int r = 0; r < 4; ++r) {
            const int n = n0 + g * 4 + r;
            dst[((size_t)b * 4096 + n) * 32 + o] = f2bf((acc[ot][r] + bias) * sc);
        }
    }
}

// ---------------- Kernel 3: v projection -> vp [B,256,4096] bf16 ----------------
__global__ __launch_bounds__(256) void k_proj_v(const unsigned short* __restrict__ xT,
                                                const float* __restrict__ Wv, const float* __restrict__ bv,
                                                unsigned short* __restrict__ vp) {
    const int b = blockIdx.z;
    const int ctile = blockIdx.y;                 // 4: c0 base
    const int ntile = blockIdx.x;                 // 64
    const int lane = threadIdx.x & 63;
    const int wv = threadIdx.x >> 6;
    const int l15 = lane & 15, g = lane >> 4;
    const int c0 = ctile * 64 + wv * 16;
    const int n0 = ntile * 64;
    const float* wrow = Wv + (size_t)(c0 + l15) * 256;
    const unsigned short* xbase = xT + ((size_t)b * 4096 + n0) * 256;

    f32x4 acc[4] = {};
    for (int k0 = 0; k0 < 256; k0 += 32) {
        const short8 a = load_w_bf16(wrow + k0 + g * 8);
#pragma unroll
        for (int nt = 0; nt < 4; ++nt) {
            const short8 bb = *(const short8*)(xbase + (size_t)(nt * 16 + l15) * 256 + k0 + g * 8);
            acc[nt] = MFMA16(a, bb, acc[nt]);
        }
    }
#pragma unroll
    for (int nt = 0; nt < 4; ++nt)
#pragma unroll
        for (int r = 0; r < 4; ++r) {
            const int c = c0 + g * 4 + r;
            const int n = n0 + nt * 16 + l15;
            vp[((size_t)b * 256 + c) * 4096 + n] = f2bf(acc[nt][r] + bv[c]);
        }
}

// ---------------- Kernel 4: flash attention, split over i, dbuf + global_load_lds ----
// S^T[i,m] = sum_d qT[i,d]*kT[m,d] (q pre-scaled by log2e); online softmax (base-2) over
// this split's i-chunk; raw partial O^T[c,m] (bf16) + per-m (m,l) stats to workspace.
__global__ __launch_bounds__(256, 5) void k_attn(const unsigned short* __restrict__ qT,
                                                 const unsigned short* __restrict__ kT,
                                                 const unsigned short* __restrict__ vp,
                                                 unsigned short* __restrict__ Opart,
                                                 float* __restrict__ mlm,
                                                 float* __restrict__ mll,
                                                 int ilen) {
    // [2 buf][256 c][32 i] bf16, 16B-chunk swizzle slot = jc ^ ((c>>1)&3); 32 KiB
    __shared__ unsigned short vlds[16384];

    const int b = blockIdx.y;
    const int mt = blockIdx.x;
    const int sp = blockIdx.z;
    const int tid = threadIdx.x;
    const int lane = tid & 63;
    const int wv = tid >> 6;
    const int l15 = lane & 15, g = lane >> 4;
    const int m_base = mt * 64 + wv * 16;
    const int i_start = sp * ilen;
    const int T = ilen >> 5;

    const unsigned short* qTb = qT + (size_t)b * 4096 * 32;
    const unsigned short* vpb = vp + (size_t)b * 256 * 4096;

    // hoisted QK^T B-frag: B[d][m'] = kT[m_base + l15][d], d = g*8..g*8+7
    const short8 qkB = *(const short8*)(kT + ((size_t)b * 4096 + m_base + l15) * 32 + g * 8);

    // staging: lane handles chunk (c = 16wv + 64s + (lane>>2), jc = lane&3); source is
    // pre-swizzled (jd) so linear global_load_lds dest yields swizzled LDS layout.
    const int jd = (lane & 3) ^ ((lane >> 3) & 3);
    const unsigned short* vsrc = vpb + (size_t)(16 * wv + (lane >> 2)) * 4096 + i_start + jd * 8;
    const int ldst0 = wv * 512;                   // element offset within buffer

#define STAGE(bufsel, ioff)                                                             \
    do {                                                                                \
        _Pragma("unroll")                                                               \
        for (int s_ = 0; s_ < 4; ++s_)                                                  \
            GLOAD_LDS16(vsrc + (size_t)s_ * 262144 + (ioff),                            \
                        vlds + (bufsel) * 8192 + ldst0 + s_ * 2048);                    \
    } while (0)

    // PV read base: slot = g ^ ((l15>>1)&3) is a per-thread constant
    const int rdbase = l15 * 32 + (g ^ ((l15 >> 1) & 3)) * 8;

    const unsigned short* qp = qTb + (size_t)(i_start + l15) * 32 + g * 8;

    f32x4 oacc[16] = {};
    float m_run = -1e30f;
    float l_run = 0.0f;

    const int srcA = l15 + 32 * (g & 1);
    const bool hi = (g >> 1) != 0;
    const f32x4 zf = {0.f, 0.f, 0.f, 0.f};

    STAGE(0, 0);
    __syncthreads();

    for (int t = 0; t < T; ++t) {
        const int cur = t & 1;
        if (t + 1 < T) STAGE(cur ^ 1, (t + 1) * 32);

        // ---- QK^T: 2 tiles of S^T [16 i x 16 m] ----
        const short8 a0 = *(const short8*)(qp);
        const short8 a1 = *(const short8*)(qp + 512);
        qp += 1024;
        f32x4 s0 = MFMA16(a0, qkB, zf);
        f32x4 s1 = MFMA16(a1, qkB, zf);

        // ---- online softmax (base-2) over i ----
        float mx = fmaxf(fmaxf(fmaxf(s0[0], s0[1]), fmaxf(s0[2], s0[3])),
                         fmaxf(fmaxf(s1[0], s1[1]), fmaxf(s1[2], s1[3])));
        mx = fmaxf(mx, __shfl_xor(mx, 16));
        mx = fmaxf(mx, __shfl_xor(mx, 32));
        const float m_new = fmaxf(m_run, mx);
        const float corr = exp2f(m_run - m_new);

        float p0[4], p1[4];
        float sum = 0.f;
#pragma unroll
        for (int r = 0; r < 4; ++r) { p0[r] = exp2f(s0[r] - m_new); sum += p0[r]; }
#pragma unroll
        for (int r = 0; r < 4; ++r) { p1[r] = exp2f(s1[r] - m_new); sum += p1[r]; }
        sum += __shfl_xor(sum, 16);
        sum += __shfl_xor(sum, 32);
        l_run = l_run * corr + sum;

        if (!__all(m_new == m_run)) {
#pragma unroll
            for (int ct = 0; ct < 16; ++ct) {
                oacc[ct][0] *= corr; oacc[ct][1] *= corr;
                oacc[ct][2] *= corr; oacc[ct][3] *= corr;
            }
        }
        m_run = m_new;

        // ---- pack P^T to bf16 + cross-lane redistribution to PV B-frag [32 i x 16 m] ----
        const unsigned int pk00 = cvt_pk_bf16(p0[0], p0[1]);
        const unsigned int pk01 = cvt_pk_bf16(p0[2], p0[3]);
        const unsigned int pk10 = cvt_pk_bf16(p1[0], p1[1]);
        const unsigned int pk11 = cvt_pk_bf16(p1[2], p1[3]);

        unsigned int wds[4];
#pragma unroll
        for (int wd = 0; wd < 4; ++wd) {
            const int src = srcA + 16 * (wd >> 1);
            const unsigned int t0 = __shfl((wd & 1) ? pk01 : pk00, src);
            const unsigned int t1 = __shfl((wd & 1) ? pk11 : pk10, src);
            wds[wd] = hi ? t1 : t0;
        }
        const u32x4 u = {wds[0], wds[1], wds[2], wds[3]};
        const short8 pb = __builtin_bit_cast(short8, u);

        // ---- PV: O^T[c][m] += V[c][i] * P^T[i][m]; addresses = base + const offsets ----
        const unsigned short* vl = vlds + cur * 8192 + rdbase;
#pragma unroll
        for (int ct = 0; ct < 16; ++ct) {
            const short8 va = *(const short8*)(vl + ct * 512);
            oacc[ct] = MFMA16(va, pb, oacc[ct]);
        }

        if (t + 1 < T) __syncthreads();
    }
#undef STAGE

    // ---- epilogue: write raw partial O (bf16) and per-m stats ----
    const int m = m_base + l15;
    unsigned short* Ob = Opart + ((size_t)(sp * 4 + b) * 256) * 4096;
#pragma unroll
    for (int ct = 0; ct < 16; ++ct)
#pragma unroll
        for (int r = 0; r < 4; ++r) {
            const int c = ct * 16 + g * 4 + r;
            Ob[(size_t)c * 4096 + m] = f2bf(oacc[ct][r]);
        }
    if (lane < 16) {
        const size_t mi = (size_t)(sp * 4 + b) * 4096 + m;
        mlm[mi] = m_run;
        mll[mi] = l_run;
    }
}

// ---------------- Kernel 5: combine partials + normalize + gamma*O + x ----------------
// grid: 4*256*4096 / (256 threads * 8 elements) = 2048 blocks
__global__ __launch_bounds__(256) void k_combine(const unsigned short* __restrict__ Opart,
                                                 const float* __restrict__ mlm,
                                                 const float* __restrict__ mll,
                                                 const float* __restrict__ x,
                                                 const float* __restrict__ gamma,
                                                 float* __restrict__ out, int S) {
    const size_t e0 = ((size_t)blockIdx.x * 256 + threadIdx.x) * 8;   // < 4,194,304
    const int m0 = (int)(e0 & 4095);
    const int b = (int)(e0 >> 20);

    float M[8];
#pragma unroll
    for (int j = 0; j < 8; ++j) M[j] = -1e30f;
    for (int s = 0; s < S; ++s) {
        const float* pm = mlm + (size_t)(s * 4 + b) * 4096 + m0;
        const float4 a = *(const float4*)pm;
        const float4 c = *(const float4*)(pm + 4);
        M[0] = fmaxf(M[0], a.x); M[1] = fmaxf(M[1], a.y);
        M[2] = fmaxf(M[2], a.z); M[3] = fmaxf(M[3], a.w);
        M[4] = fmaxf(M[4], c.x); M[5] = fmaxf(M[5], c.y);
        M[6] = fmaxf(M[6], c.z); M[7] = fmaxf(M[7], c.w);
    }

    float L[8] = {}, O[8] = {};
    for (int s = 0; s < S; ++s) {
        const size_t base = (size_t)(s * 4 + b) * 4096 + m0;
        const float4 ma = *(const float4*)(mlm + base);
        const float4 mc = *(const float4*)(mlm + base + 4);
        const float4 la = *(const float4*)(mll + base);
        const float4 lc = *(const float4*)(mll + base + 4);
        const short8 op = *(const short8*)(Opart + (size_t)s * 4194304 + e0);
        float w;
        w = exp2f(ma.x - M[0]); L[0] += w * la.x; O[0] += w * bf2f((unsigned short)op[0]);
        w = exp2f(ma.y - M[1]); L[1] += w * la.y; O[1] += w * bf2f((unsigned short)op[1]);
        w = exp2f(ma.z - M[2]); L[2] += w * la.z; O[2] += w * bf2f((unsigned short)op[2]);
        w = exp2f(ma.w - M[3]); L[3] += w * la.w; O[3] += w * bf2f((unsigned short)op[3]);
        w = exp2f(mc.x - M[4]); L[4] += w * lc.x; O[4] += w * bf2f((unsigned short)op[4]);
        w = exp2f(mc.y - M[5]); L[5] += w * lc.y; O[5] += w * bf2f((unsigned short)op[5]);
        w = exp2f(mc.z - M[6]); L[6] += w * lc.z; O[6] += w * bf2f((unsigned short)op[6]);
        w = exp2f(mc.w - M[7]); L[7] += w * lc.w; O[7] += w * bf2f((unsigned short)op[7]);
    }

    const float g0 = gamma[0];
    const float4 x0 = *(const float4*)(x + e0);
    const float4 x1 = *(const float4*)(x + e0 + 4);
    float4 o0, o1;
    o0.x = g0 * O[0] / L[0] + x0.x; o0.y = g0 * O[1] / L[1] + x0.y;
    o0.z = g0 * O[2] / L[2] + x0.z; o0.w = g0 * O[3] / L[3] + x0.w;
    o1.x = g0 * O[4] / L[4] + x1.x; o1.y = g0 * O[5] / L[5] + x1.y;
    o1.z = g0 * O[6] / L[6] + x1.z; o1.w = g0 * O[7] / L[7] + x1.w;
    *(float4*)(out + e0) = o0;
    *(float4*)(out + e0 + 4) = o1;
}

extern "C" void kernel_launch(void* const* d_in, const int* in_sizes, int n_in,
                              void* d_out, int out_size, void* d_ws, size_t ws_size,
                              hipStream_t stream) {
    (void)in_sizes; (void)n_in; (void)out_size;
    const float* x     = (const float*)d_in[0];
    const float* Wq    = (const float*)d_in[1];
    const float* bq    = (const float*)d_in[2];
    const float* Wk    = (const float*)d_in[3];
    const float* bk    = (const float*)d_in[4];
    const float* Wv    = (const float*)d_in[5];
    const float* bv    = (const float*)d_in[6];
    const float* gamma = (const float*)d_in[7];
    float* out = (float*)d_out;

    unsigned short* xT = (unsigned short*)d_ws;                       // 4*4096*256 bf16
    unsigned short* qT = xT + (size_t)4 * 4096 * 256;                 // 4*4096*32
    unsigned short* kT = qT + (size_t)4 * 4096 * 32;                  // 4*4096*32
    unsigned short* vp = kT + (size_t)4 * 4096 * 32;                  // 4*256*4096
    unsigned short* Opart = vp + (size_t)4 * 256 * 4096;              // S * 4*256*4096 bf16

    const size_t base_el = (size_t)4 * 4096 * 256 + 2 * (size_t)4 * 4096 * 32
                         + (size_t)4 * 256 * 4096;
    auto need = [&](int s) {
        return (base_el + (size_t)s * 4194304) * 2 + (size_t)2 * 131072 * 4;
    };
    const int S = (need(8) <= ws_size) ? 8 : (need(4) <= ws_size) ? 4
                : (need(2) <= ws_size) ? 2 : 1;
    float* mlm = (float*)(Opart + (size_t)S * 4194304);
    float* mll = mlm + 131072;

    k_transpose<<<dim3(128, 8, 4), 256, 0, stream>>>(x, xT);
    k_proj_qk<<<dim3(64, 4), 256, 0, stream>>>(xT, Wq, bq, Wk, bk, qT, kT);
    k_proj_v<<<dim3(64, 4, 4), 256, 0, stream>>>(xT, Wv, bv, vp);
    k_attn<<<dim3(64, 4, S), 256, 0, stream>>>(qT, kT, vp, Opart, mlm, mll, 4096 / S);
    k_combine<<<dim3(2048), 256, 0, stream>>>(Opart, mlm, mll, x, gamma, out, S);
}

// Round 5
// 120.088 us; speedup vs baseline: 1.5735x; 1.2619x over previous
//
#include <hip/hip_runtime.h>
#include <stdint.h>

typedef __attribute__((ext_vector_type(8))) short short8;        // 8 x bf16 (4 VGPRs)
typedef __attribute__((ext_vector_type(4))) float f32x4;
typedef __attribute__((ext_vector_type(4))) unsigned int u32x4;

#define MFMA16(a, b, c) __builtin_amdgcn_mfma_f32_16x16x32_bf16((a), (b), (c), 0, 0, 0)

#define GLOAD_LDS16(gsrc, ldst)                                                        \
    __builtin_amdgcn_global_load_lds(                                                  \
        (const __attribute__((address_space(1))) unsigned int*)(gsrc),                 \
        (__attribute__((address_space(3))) unsigned int*)(ldst), 16, 0, 0)

#define LOG2E 1.4426950408889634f
#define THR 11.0f

static __device__ __forceinline__ unsigned short f2bf(float f) {
    union { float f; unsigned int u; } v; v.f = f;
    unsigned int u = v.u;
    unsigned int r = 0x7fffu + ((u >> 16) & 1u);
    return (unsigned short)((u + r) >> 16);
}

static __device__ __forceinline__ float bf2f(unsigned short s) {
    union { unsigned int u; float f; } v; v.u = ((unsigned int)s) << 16;
    return v.f;
}

static __device__ __forceinline__ unsigned int cvt_pk_bf16(float lo, float hi) {
    unsigned int r;
    asm("v_cvt_pk_bf16_f32 %0, %1, %2" : "=v"(r) : "v"(lo), "v"(hi));
    return r;
}

static __device__ __forceinline__ short8 load_w_bf16(const float* row8) {
    const float4* p = (const float4*)row8;
    float4 lo = p[0], hi = p[1];
    short8 r;
    r[0] = (short)f2bf(lo.x); r[1] = (short)f2bf(lo.y);
    r[2] = (short)f2bf(lo.z); r[3] = (short)f2bf(lo.w);
    r[4] = (short)f2bf(hi.x); r[5] = (short)f2bf(hi.y);
    r[6] = (short)f2bf(hi.z); r[7] = (short)f2bf(hi.w);
    return r;
}

// ---------------- Kernel 1: x[B,256,4096] f32 -> xT[B,4096,256] bf16 ----------------
__global__ __launch_bounds__(256) void k_transpose(const float* __restrict__ x,
                                                   unsigned short* __restrict__ xT) {
    __shared__ float lds[32][33];
    const int b = blockIdx.z, ct = blockIdx.y, nt = blockIdx.x;
    const int tx = threadIdx.x & 31, ty = threadIdx.x >> 5;   // ty 0..7
    const float* xb = x + ((size_t)b * 256 + ct * 32) * 4096 + nt * 32;
#pragma unroll
    for (int k = 0; k < 4; ++k)
        lds[ty + 8 * k][tx] = xb[(size_t)(ty + 8 * k) * 4096 + tx];
    __syncthreads();
    unsigned short* o = xT + ((size_t)b * 4096 + nt * 32) * 256 + ct * 32;
#pragma unroll
    for (int k = 0; k < 4; ++k)
        o[(size_t)(ty + 8 * k) * 256 + tx] = f2bf(lds[tx][ty + 8 * k]);
}

// ---------------- Kernel 2: q/k projections -> qT,kT [B,4096,32] bf16 ----------------
// q is pre-scaled by log2(e) so attention can use exp2. 128-thread blocks, 512 blocks.
__global__ __launch_bounds__(128) void k_proj_qk(const unsigned short* __restrict__ xT,
                                                 const float* __restrict__ Wq, const float* __restrict__ bq,
                                                 const float* __restrict__ Wk, const float* __restrict__ bk,
                                                 unsigned short* __restrict__ qT,
                                                 unsigned short* __restrict__ kT) {
    const int b = blockIdx.y;
    const int ntile = blockIdx.x;                 // 32 n per block
    const int lane = threadIdx.x & 63;
    const int wv = threadIdx.x >> 6;              // 0..1
    const int l15 = lane & 15, g = lane >> 4;
    const int n0 = ntile * 32 + wv * 16;
    const unsigned short* xrow = xT + ((size_t)b * 4096 + n0 + l15) * 256;

    f32x4 acc[4] = {};
    for (int k0 = 0; k0 < 256; k0 += 32) {
        const short8 a = *(const short8*)(xrow + k0 + g * 8);
#pragma unroll
        for (int ot = 0; ot < 4; ++ot) {
            const float* wr = (ot < 2) ? (Wq + (size_t)(ot * 16 + l15) * 256)
                                       : (Wk + (size_t)((ot - 2) * 16 + l15) * 256);
            const short8 bb = load_w_bf16(wr + k0 + g * 8);
            acc[ot] = MFMA16(a, bb, acc[ot]);
        }
    }
#pragma unroll
    for (int ot = 0; ot < 4; ++ot) {
        const int o = (ot & 1) * 16 + l15;        // 0..31 within q or k
        const float bias = (ot < 2) ? bq[o] : bk[o];
        const float sc = (ot < 2) ? LOG2E : 1.0f;
        unsigned short* dst = (ot < 2) ? qT : kT;
#pragma unroll
        for (int r = 0; r < 4; ++r) {
            const int n = n0 + g * 4 + r;
            dst[((size_t)b * 4096 + n) * 32 + o] = f2bf((acc[ot][r] + bias) * sc);
        }
    }
}

// ---------------- Kernel 3: v projection -> vp [B,256,4096] bf16 ----------------
__global__ __launch_bounds__(256) void k_proj_v(const unsigned short* __restrict__ xT,
                                                const float* __restrict__ Wv, const float* __restrict__ bv,
                                                unsigned short* __restrict__ vp) {
    const int b = blockIdx.z;
    const int ctile = blockIdx.y;                 // 4: c0 base
    const int ntile = blockIdx.x;                 // 64
    const int lane = threadIdx.x & 63;
    const int wv = threadIdx.x >> 6;
    const int l15 = lane & 15, g = lane >> 4;
    const int c0 = ctile * 64 + wv * 16;
    const int n0 = ntile * 64;
    const float* wrow = Wv + (size_t)(c0 + l15) * 256;
    const unsigned short* xbase = xT + ((size_t)b * 4096 + n0) * 256;

    f32x4 acc[4] = {};
    for (int k0 = 0; k0 < 256; k0 += 32) {
        const short8 a = load_w_bf16(wrow + k0 + g * 8);
#pragma unroll
        for (int nt = 0; nt < 4; ++nt) {
            const short8 bb = *(const short8*)(xbase + (size_t)(nt * 16 + l15) * 256 + k0 + g * 8);
            acc[nt] = MFMA16(a, bb, acc[nt]);
        }
    }
#pragma unroll
    for (int nt = 0; nt < 4; ++nt)
#pragma unroll
        for (int r = 0; r < 4; ++r) {
            const int c = c0 + g * 4 + r;
            const int n = n0 + nt * 16 + l15;
            vp[((size_t)b * 256 + c) * 4096 + n] = f2bf(acc[nt][r] + bv[c]);
        }
}

// ---------------- Kernel 4: flash attention, split over i; m=32/wave (V-read reuse x2) ----
// S^T[i,m] = sum_d qT[i,d]*kT[m,d] (q pre-scaled by log2e); base-2 online softmax with
// defer-max; raw partial O^T[c,m] (bf16) + per-m (m,l) stats to workspace.
// Block: 4 waves x 32 m = 128 m, all 256 c. i-tile = 64, double-buffered 2x32KiB LDS.
__global__ __launch_bounds__(256, 2) void k_attn(const unsigned short* __restrict__ qT,
                                                 const unsigned short* __restrict__ kT,
                                                 const unsigned short* __restrict__ vp,
                                                 unsigned short* __restrict__ Opart,
                                                 float* __restrict__ mlm,
                                                 float* __restrict__ mll,
                                                 int ilen) {
    // [2 buf][256 c][64 i] bf16; 16B chunk at (c, slot) holds i-chunk jd = slot ^ swz(c),
    // swz(c) = ((c>>1)&3) | ((c&1)<<2). 64 KiB total.
    __shared__ __align__(16) unsigned short vlds[2 * 16384];

    const int b = blockIdx.y;
    const int mt = blockIdx.x;
    const int sp = blockIdx.z;
    const int tid = threadIdx.x;
    const int lane = tid & 63;
    const int wv = tid >> 6;
    const int l15 = lane & 15, g = lane >> 4;
    const int m_base = mt * 128 + wv * 32;
    const int i_start = sp * ilen;
    const int T = ilen >> 6;

    const unsigned short* qTb = qT + (size_t)b * 131072;
    const unsigned short* vpb = vp + (size_t)b * 1048576;

    // hoisted QK^T B-frags for the two m-subtiles
    const short8 qkB0 = *(const short8*)(kT + ((size_t)b * 4096 + m_base + l15) * 32 + g * 8);
    const short8 qkB1 = *(const short8*)(kT + ((size_t)b * 4096 + m_base + 16 + l15) * 32 + g * 8);

    // staging: wave wv covers rows c in [64wv, 64wv+64); lane -> (c = 64wv+8s+(lane>>3),
    // slot jc = lane&7); source pre-swizzled: jd = jc ^ swz(c) (swz reduces to lane-only).
    const int jdswz = (lane & 7) ^ ((lane >> 4) | (((lane >> 3) & 1) << 2));
    const unsigned short* vsrc = vpb + (size_t)(64 * wv + (lane >> 3)) * 4096 + i_start + jdswz * 8;
    const int ldst0 = wv * 4096;                  // element offset within buffer

#define STAGE(bufsel, ioff)                                                             \
    do {                                                                                \
        _Pragma("unroll")                                                               \
        for (int s_ = 0; s_ < 8; ++s_)                                                  \
            GLOAD_LDS16(vsrc + (size_t)s_ * 32768 + (ioff),                             \
                        vlds + (bufsel) * 16384 + ldst0 + s_ * 512);                    \
    } while (0)

    // PV read: slot = (is*4+g) ^ swz(l15); per-thread constants for is=0/1
    const int lowb = g ^ ((l15 >> 1) & 3);
    const int bta = l15 & 1;
    const int rdA = l15 * 64 + (lowb + 4 * bta) * 8;          // is = 0
    const int rdB = l15 * 64 + (lowb + 4 * (bta ^ 1)) * 8;    // is = 1

    const unsigned short* qp = qTb + (size_t)(i_start + l15) * 32 + g * 8;

    f32x4 oacc[16][2] = {};
    float m_run0 = -1e30f, m_run1 = -1e30f;
    float l_run0 = 0.0f, l_run1 = 0.0f;

    const int srcA = l15 + 32 * (g & 1);
    const bool hi = (g >> 1) != 0;
    const f32x4 zf = {0.f, 0.f, 0.f, 0.f};

    // P^T -> MFMA-B-frag redistribution (same lane mapping as verified R1/R2/R4 kernel)
    auto mk_pb = [&](const f32x4& pa, const f32x4& pc) -> short8 {
        const unsigned int k00 = cvt_pk_bf16(pa[0], pa[1]);
        const unsigned int k01 = cvt_pk_bf16(pa[2], pa[3]);
        const unsigned int k10 = cvt_pk_bf16(pc[0], pc[1]);
        const unsigned int k11 = cvt_pk_bf16(pc[2], pc[3]);
        unsigned int w[4];
#pragma unroll
        for (int wd = 0; wd < 4; ++wd) {
            const int src = srcA + 16 * (wd >> 1);
            const unsigned int t0 = __shfl((wd & 1) ? k01 : k00, src);
            const unsigned int t1 = __shfl((wd & 1) ? k11 : k10, src);
            w[wd] = hi ? t1 : t0;
        }
        const u32x4 u = {w[0], w[1], w[2], w[3]};
        return __builtin_bit_cast(short8, u);
    };

    STAGE(0, 0);
    __syncthreads();

    for (int t = 0; t < T; ++t) {
        const int cur = t & 1;
        if (t + 1 < T) STAGE(cur ^ 1, (t + 1) * 64);

        // ---- QK^T: 4 i-subtiles x 2 m-subtiles ----
        const short8 a0 = *(const short8*)(qp);
        const short8 a1 = *(const short8*)(qp + 512);
        const short8 a2 = *(const short8*)(qp + 1024);
        const short8 a3 = *(const short8*)(qp + 1536);
        qp += 2048;
        f32x4 P[4][2];
        P[0][0] = MFMA16(a0, qkB0, zf); P[0][1] = MFMA16(a0, qkB1, zf);
        P[1][0] = MFMA16(a1, qkB0, zf); P[1][1] = MFMA16(a1, qkB1, zf);
        P[2][0] = MFMA16(a2, qkB0, zf); P[2][1] = MFMA16(a2, qkB1, zf);
        P[3][0] = MFMA16(a3, qkB0, zf); P[3][1] = MFMA16(a3, qkB1, zf);

        // ---- tile max per m-subtile ----
        float mx0 = P[0][0][0], mx1 = P[0][1][0];
#pragma unroll
        for (int it = 0; it < 4; ++it)
#pragma unroll
            for (int r = 0; r < 4; ++r) {
                mx0 = fmaxf(mx0, P[it][0][r]);
                mx1 = fmaxf(mx1, P[it][1][r]);
            }
        mx0 = fmaxf(mx0, __shfl_xor(mx0, 16)); mx1 = fmaxf(mx1, __shfl_xor(mx1, 16));
        mx0 = fmaxf(mx0, __shfl_xor(mx0, 32)); mx1 = fmaxf(mx1, __shfl_xor(mx1, 32));

        // ---- defer-max: only rescale when max grew by > THR ----
        const int need = (mx0 > m_run0 + THR) || (mx1 > m_run1 + THR);
        if (__any(need)) {
            const float mn0 = fmaxf(m_run0, mx0), mn1 = fmaxf(m_run1, mx1);
            const float c0 = exp2f(m_run0 - mn0), c1 = exp2f(m_run1 - mn1);
#pragma unroll
            for (int ct = 0; ct < 16; ++ct) {
                oacc[ct][0] *= c0;
                oacc[ct][1] *= c1;
            }
            l_run0 *= c0; l_run1 *= c1;
            m_run0 = mn0; m_run1 = mn1;
        }

        // ---- P = exp2(S - m_run), row sums ----
        float sum0 = 0.f, sum1 = 0.f;
#pragma unroll
        for (int it = 0; it < 4; ++it)
#pragma unroll
            for (int r = 0; r < 4; ++r) {
                P[it][0][r] = exp2f(P[it][0][r] - m_run0); sum0 += P[it][0][r];
                P[it][1][r] = exp2f(P[it][1][r] - m_run1); sum1 += P[it][1][r];
            }
        sum0 += __shfl_xor(sum0, 16); sum1 += __shfl_xor(sum1, 16);
        sum0 += __shfl_xor(sum0, 32); sum1 += __shfl_xor(sum1, 32);
        l_run0 += sum0; l_run1 += sum1;

        // ---- PV: two 32-i halves; each V ds_read feeds 2 MFMAs (m-subtiles) ----
#pragma unroll
        for (int is = 0; is < 2; ++is) {
            const short8 pb0 = mk_pb(P[2 * is][0], P[2 * is + 1][0]);
            const short8 pb1 = mk_pb(P[2 * is][1], P[2 * is + 1][1]);
            const unsigned short* vl = vlds + cur * 16384 + (is ? rdB : rdA);
#pragma unroll
            for (int ct = 0; ct < 16; ++ct) {
                const short8 va = *(const short8*)(vl + ct * 1024);
                oacc[ct][0] = MFMA16(va, pb0, oacc[ct][0]);
                oacc[ct][1] = MFMA16(va, pb1, oacc[ct][1]);
            }
        }

        if (t + 1 < T) __syncthreads();
    }
#undef STAGE

    // ---- epilogue: write raw partial O (bf16) and per-m stats ----
    unsigned short* Ob = Opart + (size_t)(sp * 4 + b) * 1048576;
#pragma unroll
    for (int ct = 0; ct < 16; ++ct)
#pragma unroll
        for (int r = 0; r < 4; ++r) {
            const int c = ct * 16 + g * 4 + r;
            Ob[(size_t)c * 4096 + m_base + l15]      = f2bf(oacc[ct][0][r]);
            Ob[(size_t)c * 4096 + m_base + 16 + l15] = f2bf(oacc[ct][1][r]);
        }
    if (lane < 16) {
        const size_t mi = (size_t)(sp * 4 + b) * 4096 + m_base + l15;
        mlm[mi]      = m_run0;
        mll[mi]      = l_run0;
        mlm[mi + 16] = m_run1;
        mll[mi + 16] = l_run1;
    }
}

// ---------------- Kernel 5: combine partials + normalize + gamma*O + x ----------------
// grid: 4*256*4096 / (256 threads * 8 elements) = 2048 blocks
__global__ __launch_bounds__(256) void k_combine(const unsigned short* __restrict__ Opart,
                                                 const float* __restrict__ mlm,
                                                 const float* __restrict__ mll,
                                                 const float* __restrict__ x,
                                                 const float* __restrict__ gamma,
                                                 float* __restrict__ out, int S) {
    const size_t e0 = ((size_t)blockIdx.x * 256 + threadIdx.x) * 8;   // < 4,194,304
    const int m0 = (int)(e0 & 4095);
    const int b = (int)(e0 >> 20);

    float M[8];
#pragma unroll
    for (int j = 0; j < 8; ++j) M[j] = -1e30f;
    for (int s = 0; s < S; ++s) {
        const float* pm = mlm + (size_t)(s * 4 + b) * 4096 + m0;
        const float4 a = *(const float4*)pm;
        const float4 c = *(const float4*)(pm + 4);
        M[0] = fmaxf(M[0], a.x); M[1] = fmaxf(M[1], a.y);
        M[2] = fmaxf(M[2], a.z); M[3] = fmaxf(M[3], a.w);
        M[4] = fmaxf(M[4], c.x); M[5] = fmaxf(M[5], c.y);
        M[6] = fmaxf(M[6], c.z); M[7] = fmaxf(M[7], c.w);
    }

    float L[8] = {}, O[8] = {};
    for (int s = 0; s < S; ++s) {
        const size_t base = (size_t)(s * 4 + b) * 4096 + m0;
        const float4 ma = *(const float4*)(mlm + base);
        const float4 mc = *(const float4*)(mlm + base + 4);
        const float4 la = *(const float4*)(mll + base);
        const float4 lc = *(const float4*)(mll + base + 4);
        const short8 op = *(const short8*)(Opart + (size_t)s * 4194304 + e0);
        float w;
        w = exp2f(ma.x - M[0]); L[0] += w * la.x; O[0] += w * bf2f((unsigned short)op[0]);
        w = exp2f(ma.y - M[1]); L[1] += w * la.y; O[1] += w * bf2f((unsigned short)op[1]);
        w = exp2f(ma.z - M[2]); L[2] += w * la.z; O[2] += w * bf2f((unsigned short)op[2]);
        w = exp2f(ma.w - M[3]); L[3] += w * la.w; O[3] += w * bf2f((unsigned short)op[3]);
        w = exp2f(mc.x - M[4]); L[4] += w * lc.x; O[4] += w * bf2f((unsigned short)op[4]);
        w = exp2f(mc.y - M[5]); L[5] += w * lc.y; O[5] += w * bf2f((unsigned short)op[5]);
        w = exp2f(mc.z - M[6]); L[6] += w * lc.z; O[6] += w * bf2f((unsigned short)op[6]);
        w = exp2f(mc.w - M[7]); L[7] += w * lc.w; O[7] += w * bf2f((unsigned short)op[7]);
    }

    const float g0 = gamma[0];
    const float4 x0 = *(const float4*)(x + e0);
    const float4 x1 = *(const float4*)(x + e0 + 4);
    float4 o0, o1;
    o0.x = g0 * O[0] / L[0] + x0.x; o0.y = g0 * O[1] / L[1] + x0.y;
    o0.z = g0 * O[2] / L[2] + x0.z; o0.w = g0 * O[3] / L[3] + x0.w;
    o1.x = g0 * O[4] / L[4] + x1.x; o1.y = g0 * O[5] / L[5] + x1.y;
    o1.z = g0 * O[6] / L[6] + x1.z; o1.w = g0 * O[7] / L[7] + x1.w;
    *(float4*)(out + e0) = o0;
    *(float4*)(out + e0 + 4) = o1;
}

extern "C" void kernel_launch(void* const* d_in, const int* in_sizes, int n_in,
                              void* d_out, int out_size, void* d_ws, size_t ws_size,
                              hipStream_t stream) {
    (void)in_sizes; (void)n_in; (void)out_size;
    const float* x     = (const float*)d_in[0];
    const float* Wq    = (const float*)d_in[1];
    const float* bq    = (const float*)d_in[2];
    const float* Wk    = (const float*)d_in[3];
    const float* bk    = (const float*)d_in[4];
    const float* Wv    = (const float*)d_in[5];
    const float* bv    = (const float*)d_in[6];
    const float* gamma = (const float*)d_in[7];
    float* out = (float*)d_out;

    unsigned short* xT = (unsigned short*)d_ws;                       // 4*4096*256 bf16
    unsigned short* qT = xT + (size_t)4 * 4096 * 256;                 // 4*4096*32
    unsigned short* kT = qT + (size_t)4 * 4096 * 32;                  // 4*4096*32
    unsigned short* vp = kT + (size_t)4 * 4096 * 32;                  // 4*256*4096
    unsigned short* Opart = vp + (size_t)4 * 256 * 4096;              // S * 4*256*4096 bf16

    const size_t base_el = (size_t)4 * 4096 * 256 + 2 * (size_t)4 * 4096 * 32
                         + (size_t)4 * 256 * 4096;
    auto need = [&](int s) {
        return (base_el + (size_t)s * 4194304) * 2 + (size_t)2 * s * 16384 * 4;
    };
    const int S = (need(4) <= ws_size) ? 4 : (need(2) <= ws_size) ? 2 : 1;
    float* mlm = (float*)(Opart + (size_t)S * 4194304);
    float* mll = mlm + (size_t)S * 16384;

    k_transpose<<<dim3(128, 8, 4), 256, 0, stream>>>(x, xT);
    k_proj_qk<<<dim3(128, 4), 128, 0, stream>>>(xT, Wq, bq, Wk, bk, qT, kT);
    k_proj_v<<<dim3(64, 4, 4), 256, 0, stream>>>(xT, Wv, bv, vp);
    k_attn<<<dim3(32, 4, S), 256, 0, stream>>>(qT, kT, vp, Opart, mlm, mll, 4096 / S);
    k_combine<<<dim3(2048), 256, 0, stream>>>(Opart, mlm, mll, x, gamma, out, S);
}

// Round 6
// 117.961 us; speedup vs baseline: 1.6019x; 1.0180x over previous
//
#include <hip/hip_runtime.h>
#include <stdint.h>

typedef __attribute__((ext_vector_type(8))) short short8;        // 8 x bf16 (4 VGPRs)
typedef __attribute__((ext_vector_type(4))) float f32x4;
typedef __attribute__((ext_vector_type(4))) unsigned int u32x4;
typedef __attribute__((ext_vector_type(2))) unsigned int u32x2;

#define MFMA16(a, b, c) __builtin_amdgcn_mfma_f32_16x16x32_bf16((a), (b), (c), 0, 0, 0)

#define GLOAD_LDS16(gsrc, ldst)                                                        \
    __builtin_amdgcn_global_load_lds(                                                  \
        (const __attribute__((address_space(1))) unsigned int*)(gsrc),                 \
        (__attribute__((address_space(3))) unsigned int*)(ldst), 16, 0, 0)

#define LOG2E 1.4426950408889634f
#define THR 11.0f

static __device__ __forceinline__ unsigned short f2bf(float f) {
    union { float f; unsigned int u; } v; v.f = f;
    unsigned int u = v.u;
    unsigned int r = 0x7fffu + ((u >> 16) & 1u);
    return (unsigned short)((u + r) >> 16);
}

static __device__ __forceinline__ float bf2f(unsigned short s) {
    union { unsigned int u; float f; } v; v.u = ((unsigned int)s) << 16;
    return v.f;
}

static __device__ __forceinline__ unsigned int cvt_pk_bf16(float lo, float hi) {
    unsigned int r;
    asm("v_cvt_pk_bf16_f32 %0, %1, %2" : "=v"(r) : "v"(lo), "v"(hi));
    return r;
}

static __device__ __forceinline__ short8 load_w_bf16(const float* row8) {
    const float4* p = (const float4*)row8;
    float4 lo = p[0], hi = p[1];
    short8 r;
    r[0] = (short)f2bf(lo.x); r[1] = (short)f2bf(lo.y);
    r[2] = (short)f2bf(lo.z); r[3] = (short)f2bf(lo.w);
    r[4] = (short)f2bf(hi.x); r[5] = (short)f2bf(hi.y);
    r[6] = (short)f2bf(hi.z); r[7] = (short)f2bf(hi.w);
    return r;
}

// ---------------- Kernel 1: x[B,256,4096] f32 -> xT[B,4096,256] bf16 ----------------
__global__ __launch_bounds__(256) void k_transpose(const float* __restrict__ x,
                                                   unsigned short* __restrict__ xT) {
    __shared__ float lds[32][33];
    const int b = blockIdx.z, ct = blockIdx.y, nt = blockIdx.x;
    const int tx = threadIdx.x & 31, ty = threadIdx.x >> 5;   // ty 0..7
    const float* xb = x + ((size_t)b * 256 + ct * 32) * 4096 + nt * 32;
#pragma unroll
    for (int k = 0; k < 4; ++k)
        lds[ty + 8 * k][tx] = xb[(size_t)(ty + 8 * k) * 4096 + tx];
    __syncthreads();
    unsigned short* o = xT + ((size_t)b * 4096 + nt * 32) * 256 + ct * 32;
#pragma unroll
    for (int k = 0; k < 4; ++k)
        o[(size_t)(ty + 8 * k) * 256 + tx] = f2bf(lds[tx][ty + 8 * k]);
}

// ---------------- Kernel 2: q/k projections -> qT,kT [B,4096,32] bf16 ----------------
// q is pre-scaled by log2(e) so attention can use exp2.
__global__ __launch_bounds__(128) void k_proj_qk(const unsigned short* __restrict__ xT,
                                                 const float* __restrict__ Wq, const float* __restrict__ bq,
                                                 const float* __restrict__ Wk, const float* __restrict__ bk,
                                                 unsigned short* __restrict__ qT,
                                                 unsigned short* __restrict__ kT) {
    const int b = blockIdx.y;
    const int ntile = blockIdx.x;                 // 32 n per block
    const int lane = threadIdx.x & 63;
    const int wv = threadIdx.x >> 6;              // 0..1
    const int l15 = lane & 15, g = lane >> 4;
    const int n0 = ntile * 32 + wv * 16;
    const unsigned short* xrow = xT + ((size_t)b * 4096 + n0 + l15) * 256;

    f32x4 acc[4] = {};
    for (int k0 = 0; k0 < 256; k0 += 32) {
        const short8 a = *(const short8*)(xrow + k0 + g * 8);
#pragma unroll
        for (int ot = 0; ot < 4; ++ot) {
            const float* wr = (ot < 2) ? (Wq + (size_t)(ot * 16 + l15) * 256)
                                       : (Wk + (size_t)((ot - 2) * 16 + l15) * 256);
            const short8 bb = load_w_bf16(wr + k0 + g * 8);
            acc[ot] = MFMA16(a, bb, acc[ot]);
        }
    }
#pragma unroll
    for (int ot = 0; ot < 4; ++ot) {
        const int o = (ot & 1) * 16 + l15;        // 0..31 within q or k
        const float bias = (ot < 2) ? bq[o] : bk[o];
        const float sc = (ot < 2) ? LOG2E : 1.0f;
        unsigned short* dst = (ot < 2) ? qT : kT;
#pragma unroll
        for (int r = 0; r < 4; ++r) {
            const int n = n0 + g * 4 + r;
            dst[((size_t)b * 4096 + n) * 32 + o] = f2bf((acc[ot][r] + bias) * sc);
        }
    }
}

// ---------------- Kernel 3: v projection -> vp [B,256,4096] bf16 ----------------
__global__ __launch_bounds__(256) void k_proj_v(const unsigned short* __restrict__ xT,
                                                const float* __restrict__ Wv, const float* __restrict__ bv,
                                                unsigned short* __restrict__ vp) {
    const int b = blockIdx.z;
    const int ctile = blockIdx.y;                 // 4: c0 base
    const int ntile = blockIdx.x;                 // 64
    const int lane = threadIdx.x & 63;
    const int wv = threadIdx.x >> 6;
    const int l15 = lane & 15, g = lane >> 4;
    const int c0 = ctile * 64 + wv * 16;
    const int n0 = ntile * 64;
    const float* wrow = Wv + (size_t)(c0 + l15) * 256;
    const unsigned short* xbase = xT + ((size_t)b * 4096 + n0) * 256;

    f32x4 acc[4] = {};
    for (int k0 = 0; k0 < 256; k0 += 32) {
        const short8 a = load_w_bf16(wrow + k0 + g * 8);
#pragma unroll
        for (int nt = 0; nt < 4; ++nt) {
            const short8 bb = *(const short8*)(xbase + (size_t)(nt * 16 + l15) * 256 + k0 + g * 8);
            acc[nt] = MFMA16(a, bb, acc[nt]);
        }
    }
#pragma unroll
    for (int nt = 0; nt < 4; ++nt)
#pragma unroll
        for (int r = 0; r < 4; ++r) {
            const int c = c0 + g * 4 + r;
            const int n = n0 + nt * 16 + l15;
            vp[((size_t)b * 256 + c) * 4096 + n] = f2bf(acc[nt][r] + bv[c]);
        }
}

// ---------------- Kernel 4: flash attention; m=32/wave; shuffle-free PV ----------------
// Custom MFMA k-order: k-slot j of group g <-> i = 32*is + 4g + (j&3) + 16*(j>>2).
// B-frag (P^T) is then each lane's OWN QK output (quadrant-native) -> no cross-lane ops.
// A-frag (V) = two ds_read_b64 per (is,ct) at per-thread-constant swizzled offsets.
__global__ __launch_bounds__(256, 2) void k_attn(const unsigned short* __restrict__ qT,
                                                 const unsigned short* __restrict__ kT,
                                                 const unsigned short* __restrict__ vp,
                                                 unsigned short* __restrict__ Opart,
                                                 float* __restrict__ mlm,
                                                 float* __restrict__ mll,
                                                 int ilen) {
    // [2 buf][256 c][64 i] bf16; 16B chunk (c, slot) holds i-chunk jd = slot ^ (c&7). 64 KiB.
    __shared__ __align__(16) unsigned short vlds[2 * 16384];

    const int b = blockIdx.y;
    const int mt = blockIdx.x;
    const int sp = blockIdx.z;
    const int tid = threadIdx.x;
    const int lane = tid & 63;
    const int wv = tid >> 6;
    const int l15 = lane & 15, g = lane >> 4;
    const int m_base = mt * 128 + wv * 32;
    const int i_start = sp * ilen;
    const int T = ilen >> 6;

    const unsigned short* qTb = qT + (size_t)b * 131072;
    const unsigned short* vpb = vp + (size_t)b * 1048576;

    // hoisted QK^T B-frags for the two m-subtiles
    const short8 qkB0 = *(const short8*)(kT + ((size_t)b * 4096 + m_base + l15) * 32 + g * 8);
    const short8 qkB1 = *(const short8*)(kT + ((size_t)b * 4096 + m_base + 16 + l15) * 32 + g * 8);

    // staging: lane -> (c = 64wv + 8s + (lane>>3), slot jc = lane&7); source pre-swizzled:
    // jd = jc ^ (c&7) = (lane&7) ^ ((lane>>3)&7)  (lane-only -> hoistable pointer).
    const int jd = (lane & 7) ^ ((lane >> 3) & 7);
    const unsigned short* vsrc = vpb + (size_t)(64 * wv + (lane >> 3)) * 4096 + i_start + jd * 8;
    const int ldst0 = wv * 4096;                  // element offset within buffer

#define STAGE(bufsel, ioff)                                                             \
    do {                                                                                \
        _Pragma("unroll")                                                               \
        for (int s_ = 0; s_ < 8; ++s_)                                                  \
            GLOAD_LDS16(vsrc + (size_t)s_ * 32768 + (ioff),                             \
                        vlds + (bufsel) * 16384 + ldst0 + s_ * 512);                    \
    } while (0)

    // PV A-frag read offsets (elements): two b64 per (is); 16B-chunk jd16 = 4is+2h+(g>>1),
    // slot = jd16 ^ (l15&7), 8B-half = g&1. Per-thread constants.
    const int swz = l15 & 7;
    const int rbase = l15 * 64 + (g & 1) * 4;
    const int rd00 = rbase + (((0 | (g >> 1)) ^ swz) << 3);          // is=0,h=0
    const int rd01 = rbase + (((2 | (g >> 1)) ^ swz) << 3);          // is=0,h=1
    const int rd10 = rbase + (((4 | (g >> 1)) ^ swz) << 3);          // is=1,h=0
    const int rd11 = rbase + (((6 | (g >> 1)) ^ swz) << 3);          // is=1,h=1

    const unsigned short* qp = qTb + (size_t)(i_start + l15) * 32 + g * 8;

    f32x4 oacc[16][2] = {};
    float m_run0 = -1e30f, m_run1 = -1e30f;
    float l_run0 = 0.0f, l_run1 = 0.0f;
    const f32x4 zf = {0.f, 0.f, 0.f, 0.f};

    STAGE(0, 0);
    __syncthreads();

    for (int t = 0; t < T; ++t) {
        const int cur = t & 1;
        if (t + 1 < T) STAGE(cur ^ 1, (t + 1) * 64);

        // ---- QK^T: 4 i-subtiles x 2 m-subtiles ----
        const short8 a0 = *(const short8*)(qp);
        const short8 a1 = *(const short8*)(qp + 512);
        const short8 a2 = *(const short8*)(qp + 1024);
        const short8 a3 = *(const short8*)(qp + 1536);
        qp += 2048;
        f32x4 P[4][2];
        P[0][0] = MFMA16(a0, qkB0, zf); P[0][1] = MFMA16(a0, qkB1, zf);
        P[1][0] = MFMA16(a1, qkB0, zf); P[1][1] = MFMA16(a1, qkB1, zf);
        P[2][0] = MFMA16(a2, qkB0, zf); P[2][1] = MFMA16(a2, qkB1, zf);
        P[3][0] = MFMA16(a3, qkB0, zf); P[3][1] = MFMA16(a3, qkB1, zf);

        // ---- tile max per m-subtile ----
        float mx0 = P[0][0][0], mx1 = P[0][1][0];
#pragma unroll
        for (int it = 0; it < 4; ++it)
#pragma unroll
            for (int r = 0; r < 4; ++r) {
                mx0 = fmaxf(mx0, P[it][0][r]);
                mx1 = fmaxf(mx1, P[it][1][r]);
            }
        mx0 = fmaxf(mx0, __shfl_xor(mx0, 16)); mx1 = fmaxf(mx1, __shfl_xor(mx1, 16));
        mx0 = fmaxf(mx0, __shfl_xor(mx0, 32)); mx1 = fmaxf(mx1, __shfl_xor(mx1, 32));

        // ---- defer-max: only rescale when max grew by > THR ----
        const int need = (mx0 > m_run0 + THR) || (mx1 > m_run1 + THR);
        if (__any(need)) {
            const float mn0 = fmaxf(m_run0, mx0), mn1 = fmaxf(m_run1, mx1);
            const float c0 = exp2f(m_run0 - mn0), c1 = exp2f(m_run1 - mn1);
#pragma unroll
            for (int ct = 0; ct < 16; ++ct) {
                oacc[ct][0] *= c0;
                oacc[ct][1] *= c1;
            }
            l_run0 *= c0; l_run1 *= c1;
            m_run0 = mn0; m_run1 = mn1;
        }

        // ---- P = exp2(S - m_run), row sums ----
        float sum0 = 0.f, sum1 = 0.f;
#pragma unroll
        for (int it = 0; it < 4; ++it)
#pragma unroll
            for (int r = 0; r < 4; ++r) {
                P[it][0][r] = exp2f(P[it][0][r] - m_run0); sum0 += P[it][0][r];
                P[it][1][r] = exp2f(P[it][1][r] - m_run1); sum1 += P[it][1][r];
            }
        sum0 += __shfl_xor(sum0, 16); sum1 += __shfl_xor(sum1, 16);
        sum0 += __shfl_xor(sum0, 32); sum1 += __shfl_xor(sum1, 32);
        l_run0 += sum0; l_run1 += sum1;

        // ---- PV: B-frag = lane-local pack (k-order native to QK quadrants) ----
        const unsigned short* vbase = vlds + cur * 16384;
#pragma unroll
        for (int is = 0; is < 2; ++is) {
            const u32x4 ub0 = {cvt_pk_bf16(P[2 * is][0][0], P[2 * is][0][1]),
                               cvt_pk_bf16(P[2 * is][0][2], P[2 * is][0][3]),
                               cvt_pk_bf16(P[2 * is + 1][0][0], P[2 * is + 1][0][1]),
                               cvt_pk_bf16(P[2 * is + 1][0][2], P[2 * is + 1][0][3])};
            const u32x4 ub1 = {cvt_pk_bf16(P[2 * is][1][0], P[2 * is][1][1]),
                               cvt_pk_bf16(P[2 * is][1][2], P[2 * is][1][3]),
                               cvt_pk_bf16(P[2 * is + 1][1][0], P[2 * is + 1][1][1]),
                               cvt_pk_bf16(P[2 * is + 1][1][2], P[2 * is + 1][1][3])};
            const short8 pb0 = __builtin_bit_cast(short8, ub0);
            const short8 pb1 = __builtin_bit_cast(short8, ub1);
            const unsigned short* p0 = vbase + (is ? rd10 : rd00);
            const unsigned short* p1 = vbase + (is ? rd11 : rd01);
#pragma unroll
            for (int ct = 0; ct < 16; ++ct) {
                const u32x2 vlo = *(const u32x2*)(p0 + ct * 1024);
                const u32x2 vhi = *(const u32x2*)(p1 + ct * 1024);
                const u32x4 uv = {vlo[0], vlo[1], vhi[0], vhi[1]};
                const short8 va = __builtin_bit_cast(short8, uv);
                oacc[ct][0] = MFMA16(va, pb0, oacc[ct][0]);
                oacc[ct][1] = MFMA16(va, pb1, oacc[ct][1]);
            }
        }

        if (t + 1 < T) __syncthreads();
    }
#undef STAGE

    // ---- epilogue: write raw partial O (bf16) and per-m stats ----
    unsigned short* Ob = Opart + (size_t)(sp * 4 + b) * 1048576;
#pragma unroll
    for (int ct = 0; ct < 16; ++ct)
#pragma unroll
        for (int r = 0; r < 4; ++r) {
            const int c = ct * 16 + g * 4 + r;
            Ob[(size_t)c * 4096 + m_base + l15]      = f2bf(oacc[ct][0][r]);
            Ob[(size_t)c * 4096 + m_base + 16 + l15] = f2bf(oacc[ct][1][r]);
        }
    if (lane < 16) {
        const size_t mi = (size_t)(sp * 4 + b) * 4096 + m_base + l15;
        mlm[mi]      = m_run0;
        mll[mi]      = l_run0;
        mlm[mi + 16] = m_run1;
        mll[mi + 16] = l_run1;
    }
}

// ---------------- Kernel 5: combine partials + normalize + gamma*O + x ----------------
// grid: 4*256*4096 / (256 threads * 8 elements) = 2048 blocks
__global__ __launch_bounds__(256) void k_combine(const unsigned short* __restrict__ Opart,
                                                 const float* __restrict__ mlm,
                                                 const float* __restrict__ mll,
                                                 const float* __restrict__ x,
                                                 const float* __restrict__ gamma,
                                                 float* __restrict__ out, int S) {
    const size_t e0 = ((size_t)blockIdx.x * 256 + threadIdx.x) * 8;   // < 4,194,304
    const int m0 = (int)(e0 & 4095);
    const int b = (int)(e0 >> 20);

    float M[8];
#pragma unroll
    for (int j = 0; j < 8; ++j) M[j] = -1e30f;
    for (int s = 0; s < S; ++s) {
        const float* pm = mlm + (size_t)(s * 4 + b) * 4096 + m0;
        const float4 a = *(const float4*)pm;
        const float4 c = *(const float4*)(pm + 4);
        M[0] = fmaxf(M[0], a.x); M[1] = fmaxf(M[1], a.y);
        M[2] = fmaxf(M[2], a.z); M[3] = fmaxf(M[3], a.w);
        M[4] = fmaxf(M[4], c.x); M[5] = fmaxf(M[5], c.y);
        M[6] = fmaxf(M[6], c.z); M[7] = fmaxf(M[7], c.w);
    }

    float L[8] = {}, O[8] = {};
    for (int s = 0; s < S; ++s) {
        const size_t base = (size_t)(s * 4 + b) * 4096 + m0;
        const float4 ma = *(const float4*)(mlm + base);
        const float4 mc = *(const float4*)(mlm + base + 4);
        const float4 la = *(const float4*)(mll + base);
        const float4 lc = *(const float4*)(mll + base + 4);
        const short8 op = *(const short8*)(Opart + (size_t)s * 4194304 + e0);
        float w;
        w = exp2f(ma.x - M[0]); L[0] += w * la.x; O[0] += w * bf2f((unsigned short)op[0]);
        w = exp2f(ma.y - M[1]); L[1] += w * la.y; O[1] += w * bf2f((unsigned short)op[1]);
        w = exp2f(ma.z - M[2]); L[2] += w * la.z; O[2] += w * bf2f((unsigned short)op[2]);
        w = exp2f(ma.w - M[3]); L[3] += w * la.w; O[3] += w * bf2f((unsigned short)op[3]);
        w = exp2f(mc.x - M[4]); L[4] += w * lc.x; O[4] += w * bf2f((unsigned short)op[4]);
        w = exp2f(mc.y - M[5]); L[5] += w * lc.y; O[5] += w * bf2f((unsigned short)op[5]);
        w = exp2f(mc.z - M[6]); L[6] += w * lc.z; O[6] += w * bf2f((unsigned short)op[6]);
        w = exp2f(mc.w - M[7]); L[7] += w * lc.w; O[7] += w * bf2f((unsigned short)op[7]);
    }

    const float g0 = gamma[0];
    const float4 x0 = *(const float4*)(x + e0);
    const float4 x1 = *(const float4*)(x + e0 + 4);
    float4 o0, o1;
    o0.x = g0 * O[0] / L[0] + x0.x; o0.y = g0 * O[1] / L[1] + x0.y;
    o0.z = g0 * O[2] / L[2] + x0.z; o0.w = g0 * O[3] / L[3] + x0.w;
    o1.x = g0 * O[4] / L[4] + x1.x; o1.y = g0 * O[5] / L[5] + x1.y;
    o1.z = g0 * O[6] / L[6] + x1.z; o1.w = g0 * O[7] / L[7] + x1.w;
    *(float4*)(out + e0) = o0;
    *(float4*)(out + e0 + 4) = o1;
}

extern "C" void kernel_launch(void* const* d_in, const int* in_sizes, int n_in,
                              void* d_out, int out_size, void* d_ws, size_t ws_size,
                              hipStream_t stream) {
    (void)in_sizes; (void)n_in; (void)out_size;
    const float* x     = (const float*)d_in[0];
    const float* Wq    = (const float*)d_in[1];
    const float* bq    = (const float*)d_in[2];
    const float* Wk    = (const float*)d_in[3];
    const float* bk    = (const float*)d_in[4];
    const float* Wv    = (const float*)d_in[5];
    const float* bv    = (const float*)d_in[6];
    const float* gamma = (const float*)d_in[7];
    float* out = (float*)d_out;

    unsigned short* xT = (unsigned short*)d_ws;                       // 4*4096*256 bf16
    unsigned short* qT = xT + (size_t)4 * 4096 * 256;                 // 4*4096*32
    unsigned short* kT = qT + (size_t)4 * 4096 * 32;                  // 4*4096*32
    unsigned short* vp = kT + (size_t)4 * 4096 * 32;                  // 4*256*4096
    unsigned short* Opart = vp + (size_t)4 * 256 * 4096;              // S * 4*256*4096 bf16

    const size_t base_el = (size_t)4 * 4096 * 256 + 2 * (size_t)4 * 4096 * 32
                         + (size_t)4 * 256 * 4096;
    auto need = [&](int s) {
        return (base_el + (size_t)s * 4194304) * 2 + (size_t)2 * s * 16384 * 4;
    };
    const int S = (need(4) <= ws_size) ? 4 : (need(2) <= ws_size) ? 2 : 1;
    float* mlm = (float*)(Opart + (size_t)S * 4194304);
    float* mll = mlm + (size_t)S * 16384;

    k_transpose<<<dim3(128, 8, 4), 256, 0, stream>>>(x, xT);
    k_proj_qk<<<dim3(128, 4), 128, 0, stream>>>(xT, Wq, bq, Wk, bk, qT, kT);
    k_proj_v<<<dim3(64, 4, 4), 256, 0, stream>>>(xT, Wv, bv, vp);
    k_attn<<<dim3(32, 4, S), 256, 0, stream>>>(qT, kT, vp, Opart, mlm, mll, 4096 / S);
    k_combine<<<dim3(2048), 256, 0, stream>>>(Opart, mlm, mll, x, gamma, out, S);
}